// Round 1
// baseline (893.635 us; speedup 1.0000x reference)
//
#include <hip/hip_runtime.h>
#include <hip/hip_bf16.h>
#include <math.h>

#define BB 32
#define SS 4096
#define EE 512
#define AA 512

typedef short bf16x8 __attribute__((ext_vector_type(8)));
typedef float f32x4 __attribute__((ext_vector_type(4)));
typedef unsigned short u16x4 __attribute__((ext_vector_type(4)));

__device__ __forceinline__ unsigned short f2bf(float f) {
  unsigned int u = __float_as_uint(f);
  u += 0x7fffu + ((u >> 16) & 1u);   // round-to-nearest-even (inputs are finite normals)
  return (unsigned short)(u >> 16);
}

__device__ __forceinline__ float tanh_fast(float x) {
  // 1 - 2/(e^{2x}+1); saturates correctly at +/-inf of expf
  return 1.f - 2.f / (__expf(2.f * x) + 1.f);
}

__global__ void zero_ctx_kernel(float* __restrict__ ctx) {
  int i = blockIdx.x * 256 + threadIdx.x;
  ctx[i] = 0.f;   // grid 64 x 256 == 16384 exactly
}

// q[b][a] = sum_e h[b][e] * Wh[e][a]   (f32, tiny)
__global__ void query_kernel(const float* __restrict__ h,
                             const float* __restrict__ Wh,
                             float* __restrict__ q) {
  __shared__ float hrow[EE];
  int b = blockIdx.x;
  int t = threadIdx.x;
  for (int i = t; i < EE; i += 256) hrow[i] = h[b * EE + i];
  __syncthreads();
  float a0 = 0.f, a1 = 0.f;
  for (int e = 0; e < EE; ++e) {
    float hv = hrow[e];
    a0 += hv * Wh[e * AA + t];
    a1 += hv * Wh[e * AA + t + 256];
  }
  q[b * AA + t] = a0;
  q[b * AA + t + 256] = a1;
}

// Wst[a][e] = bf16(Ws[e][a])
__global__ void wst_kernel(const float* __restrict__ Ws,
                           unsigned short* __restrict__ Wst) {
  int i = blockIdx.x * 256 + threadIdx.x;   // over 512*512
  int a = i >> 9, e = i & 511;
  Wst[a * EE + e] = f2bf(Ws[e * AA + a]);
}

// Per block: b = blockIdx.y, rows s0..s0+63. Computes raw scores (pre-mask).
__global__ __launch_bounds__(256) void scores_kernel(
    const float* __restrict__ enc, const unsigned short* __restrict__ Wst,
    const float* __restrict__ q, const float* __restrict__ v,
    float* __restrict__ scores) {
  // 64 rows x 512 k, bf16, XOR-swizzled 16B chunks: chunk' = chunk ^ (row&7).
  // Exactly 64KB -> 2 blocks/CU.
  __shared__ __align__(16) unsigned short Atile[64 * 512];
  const int b = blockIdx.y;
  const int s0 = blockIdx.x * 64;
  const int tid = threadIdx.x;

  // ---- stage enc tile (f32 -> bf16) ----
  const float4* src = (const float4*)(enc + ((size_t)b * SS + s0) * EE);
  for (int i = 0; i < 32; ++i) {
    int idx = i * 256 + tid;        // 0..8191 float4s
    float4 x = src[idx];
    int row = idx >> 7;             // 128 float4 per row
    int c4 = idx & 127;
    int chunk = c4 >> 1;            // 8 bf16 per chunk
    int within = (c4 & 1) * 4;
    int cs = chunk ^ (row & 7);
    u16x4 p;
    p.x = f2bf(x.x); p.y = f2bf(x.y); p.z = f2bf(x.z); p.w = f2bf(x.w);
    *(u16x4*)&Atile[row * 512 + cs * 8 + within] = p;
  }
  __syncthreads();

  const int w = tid >> 6, lane = tid & 63;
  const int quad = lane >> 4, l16 = lane & 15;
  const int rowLocal = w * 16 + l16;          // A-operand row for this lane
  const unsigned short* arow = &Atile[rowLocal * 512];

  float sAcc[4] = {0.f, 0.f, 0.f, 0.f};       // partial scores, rows w*16+quad*4+r

  for (int nc = 0; nc < 16; ++nc) {
    const int n0 = nc * 32;
    f32x4 acc0 = {0.f, 0.f, 0.f, 0.f};
    f32x4 acc1 = {0.f, 0.f, 0.f, 0.f};
    const unsigned short* wb0 = Wst + (size_t)(n0 + l16) * EE + quad * 8;
    const unsigned short* wb1 = wb0 + 16 * EE;
#pragma unroll
    for (int k0 = 0; k0 < 512; k0 += 32) {
      int chunk = (k0 >> 3) + quad;
      int cs = chunk ^ (l16 & 7);
      bf16x8 a  = *(const bf16x8*)&arow[cs * 8];
      bf16x8 b0 = *(const bf16x8*)&wb0[k0];
      bf16x8 b1 = *(const bf16x8*)&wb1[k0];
      acc0 = __builtin_amdgcn_mfma_f32_16x16x32_bf16(a, b0, acc0, 0, 0, 0);
      acc1 = __builtin_amdgcn_mfma_f32_16x16x32_bf16(a, b1, acc1, 0, 0, 0);
    }
    float q0 = q[b * AA + n0 + l16], q1 = q[b * AA + n0 + 16 + l16];
    float v0 = v[n0 + l16],          v1 = v[n0 + 16 + l16];
#pragma unroll
    for (int r = 0; r < 4; ++r) {
      sAcc[r] += tanh_fast(q0 + acc0[r]) * v0 + tanh_fast(q1 + acc1[r]) * v1;
    }
  }

  // reduce over the 16 columns held by the 16 lanes of each quad-group
#pragma unroll
  for (int r = 0; r < 4; ++r) {
    float vs = sAcc[r];
    vs += __shfl_xor(vs, 1, 64);
    vs += __shfl_xor(vs, 2, 64);
    vs += __shfl_xor(vs, 4, 64);
    vs += __shfl_xor(vs, 8, 64);
    if (l16 == 0)
      scores[(size_t)b * SS + s0 + w * 16 + quad * 4 + r] = vs;
  }
}

// one block per b: mask, softmax, in-place over the attn region
__global__ void softmax_kernel(const int* __restrict__ mask,
                               float* __restrict__ attn) {
  __shared__ float red[8];
  int b = blockIdx.x, t = threadIdx.x;
  float vals[16];
  float m = -1e30f;
  float* row = attn + (size_t)b * SS;
  const int* mrow = mask + (size_t)b * SS;
#pragma unroll
  for (int i = 0; i < 16; ++i) {
    int s = i * 256 + t;
    float x = mrow[s] ? -1e9f : row[s];
    vals[i] = x;
    m = fmaxf(m, x);
  }
  for (int off = 1; off < 64; off <<= 1) m = fmaxf(m, __shfl_xor(m, off, 64));
  int wv = t >> 6, ln = t & 63;
  if (ln == 0) red[wv] = m;
  __syncthreads();
  m = fmaxf(fmaxf(red[0], red[1]), fmaxf(red[2], red[3]));
  float sum = 0.f;
#pragma unroll
  for (int i = 0; i < 16; ++i) { vals[i] = __expf(vals[i] - m); sum += vals[i]; }
  for (int off = 1; off < 64; off <<= 1) sum += __shfl_xor(sum, off, 64);
  if (ln == 0) red[4 + wv] = sum;
  __syncthreads();
  sum = red[4] + red[5] + red[6] + red[7];
  float inv = 1.f / sum;
#pragma unroll
  for (int i = 0; i < 16; ++i) row[i * 256 + t] = vals[i] * inv;
}

// ctx[b][e] = sum_s attn[b][s] * enc[b][s][e]; grid (8 s-chunks, 32 b)
__global__ void ctx_kernel(const float* __restrict__ enc,
                           const float* __restrict__ attn,
                           float* __restrict__ ctx) {
  int b = blockIdx.y;
  int sc = blockIdx.x;
  int t = threadIdx.x;
  int e0 = t * 2;
  const float* encb = enc + (size_t)b * SS * EE;
  const float* arow = attn + (size_t)b * SS;
  float ax = 0.f, ay = 0.f;
  for (int i = 0; i < 512; ++i) {
    int s = sc * 512 + i;
    float wgt = arow[s];
    float2 ev = *(const float2*)&encb[(size_t)s * EE + e0];
    ax += wgt * ev.x;
    ay += wgt * ev.y;
  }
  atomicAdd(&ctx[b * EE + e0], ax);
  atomicAdd(&ctx[b * EE + e0 + 1], ay);
}

extern "C" void kernel_launch(void* const* d_in, const int* in_sizes, int n_in,
                              void* d_out, int out_size, void* d_ws, size_t ws_size,
                              hipStream_t stream) {
  const float* h    = (const float*)d_in[0];
  const float* enc  = (const float*)d_in[1];
  const int*   mask = (const int*)d_in[2];
  const float* Wh   = (const float*)d_in[3];
  const float* Ws   = (const float*)d_in[4];
  const float* v    = (const float*)d_in[5];

  float* out  = (float*)d_out;
  float* ctx  = out;              // [32,512]
  float* attn = out + BB * EE;    // [32,4096]

  float* qws = (float*)d_ws;                                            // 64 KB
  unsigned short* Wst =
      (unsigned short*)((char*)d_ws + (size_t)BB * AA * sizeof(float)); // 512 KB

  hipLaunchKernelGGL(zero_ctx_kernel, dim3(64), dim3(256), 0, stream, ctx);
  hipLaunchKernelGGL(query_kernel, dim3(32), dim3(256), 0, stream, h, Wh, qws);
  hipLaunchKernelGGL(wst_kernel, dim3(1024), dim3(256), 0, stream, Ws, Wst);
  hipLaunchKernelGGL(scores_kernel, dim3(SS / 64, BB), dim3(256), 0, stream,
                     enc, Wst, qws, v, attn);
  hipLaunchKernelGGL(softmax_kernel, dim3(BB), dim3(256), 0, stream, mask, attn);
  hipLaunchKernelGGL(ctx_kernel, dim3(8, BB), dim3(256), 0, stream, enc, attn, ctx);
}

// Round 2
// 798.367 us; speedup vs baseline: 1.1193x; 1.1193x over previous
//
#include <hip/hip_runtime.h>
#include <hip/hip_bf16.h>
#include <math.h>

#define BB 32
#define SS 4096
#define EE 512
#define AA 512

typedef short bf16x8 __attribute__((ext_vector_type(8)));
typedef float f32x4 __attribute__((ext_vector_type(4)));
typedef unsigned short u16x4 __attribute__((ext_vector_type(4)));

__device__ __forceinline__ unsigned short f2bf(float f) {
  unsigned int u = __float_as_uint(f);
  u += 0x7fffu + ((u >> 16) & 1u);   // round-to-nearest-even (finite normals)
  return (unsigned short)(u >> 16);
}

__device__ __forceinline__ float tanh_fast(float x) {
  return 1.f - 2.f / (__expf(2.f * x) + 1.f);
}

// q[b][a] = sum_e h[b][e] * Wh[e][a]   (f32, tiny)
__global__ void query_kernel(const float* __restrict__ h,
                             const float* __restrict__ Wh,
                             float* __restrict__ q) {
  __shared__ float hrow[EE];
  int b = blockIdx.x;
  int t = threadIdx.x;
  for (int i = t; i < EE; i += 256) hrow[i] = h[b * EE + i];
  __syncthreads();
  float a0 = 0.f, a1 = 0.f;
  for (int e = 0; e < EE; ++e) {
    float hv = hrow[e];
    a0 += hv * Wh[e * AA + t];
    a1 += hv * Wh[e * AA + t + 256];
  }
  q[b * AA + t] = a0;
  q[b * AA + t + 256] = a1;
}

// Wst[a][e] = bf16(Ws[e][a])
__global__ void wst_kernel(const float* __restrict__ Ws,
                           unsigned short* __restrict__ Wst) {
  int i = blockIdx.x * 256 + threadIdx.x;   // over 512*512
  int a = i >> 9, e = i & 511;
  Wst[a * EE + e] = f2bf(Ws[e * AA + a]);
}

// Block: b = blockIdx.y, 32 rows starting s0. 4 waves split N (128 cols each).
// 32 KB LDS A-tile -> 4 blocks/CU (16 waves/CU).
__global__ __launch_bounds__(256, 4) void scores_kernel(
    const float* __restrict__ enc, const unsigned short* __restrict__ Wst,
    const float* __restrict__ q, const float* __restrict__ v,
    float* __restrict__ scores) {
  // 32 rows x 512 k bf16, XOR-swizzled 16B chunks: chunk' = chunk ^ (row&7).
  __shared__ __align__(16) unsigned short Atile[32 * 512];
  __shared__ float spart[4][32];
  const int b = blockIdx.y;
  const int s0 = blockIdx.x * 32;
  const int tid = threadIdx.x;

  // ---- stage enc tile (f32 -> bf16), 4096 float4, 16 per thread ----
  const float4* src = (const float4*)(enc + ((size_t)b * SS + s0) * EE);
#pragma unroll
  for (int i = 0; i < 16; ++i) {
    int idx = i * 256 + tid;        // 0..4095 float4s
    float4 x = src[idx];
    int row = idx >> 7;             // 128 float4 per row
    int c4 = idx & 127;
    int chunk = c4 >> 1;            // 8 bf16 per 16B chunk
    int within = (c4 & 1) * 4;
    int cs = chunk ^ (row & 7);
    u16x4 p;
    p.x = f2bf(x.x); p.y = f2bf(x.y); p.z = f2bf(x.z); p.w = f2bf(x.w);
    *(u16x4*)&Atile[row * 512 + cs * 8 + within] = p;
  }
  __syncthreads();

  const int w = tid >> 6, lane = tid & 63;
  const int quad = lane >> 4, l16 = lane & 15;
  const unsigned short* arow0 = &Atile[l16 * 512];         // rows 0..15
  const unsigned short* arow1 = &Atile[(16 + l16) * 512];  // rows 16..31

  float sAcc0[4] = {0.f, 0.f, 0.f, 0.f};   // rows quad*4+r
  float sAcc1[4] = {0.f, 0.f, 0.f, 0.f};   // rows 16+quad*4+r

  for (int j = 0; j < 4; ++j) {
    const int n0 = w * 128 + j * 32;
    f32x4 acc00 = {0.f, 0.f, 0.f, 0.f};   // rows0 x cols n0..n0+15
    f32x4 acc01 = {0.f, 0.f, 0.f, 0.f};   // rows0 x cols n0+16..n0+31
    f32x4 acc10 = {0.f, 0.f, 0.f, 0.f};   // rows1 x cols lo
    f32x4 acc11 = {0.f, 0.f, 0.f, 0.f};   // rows1 x cols hi
    const unsigned short* wb0 = Wst + (size_t)(n0 + l16) * EE + quad * 8;
    const unsigned short* wb1 = wb0 + 16 * EE;
#pragma unroll
    for (int k0 = 0; k0 < 512; k0 += 32) {
      int cs = ((k0 >> 3) + quad) ^ (l16 & 7);
      bf16x8 a0 = *(const bf16x8*)&arow0[cs * 8];
      bf16x8 a1 = *(const bf16x8*)&arow1[cs * 8];
      bf16x8 b0 = *(const bf16x8*)&wb0[k0];
      bf16x8 b1 = *(const bf16x8*)&wb1[k0];
      acc00 = __builtin_amdgcn_mfma_f32_16x16x32_bf16(a0, b0, acc00, 0, 0, 0);
      acc01 = __builtin_amdgcn_mfma_f32_16x16x32_bf16(a0, b1, acc01, 0, 0, 0);
      acc10 = __builtin_amdgcn_mfma_f32_16x16x32_bf16(a1, b0, acc10, 0, 0, 0);
      acc11 = __builtin_amdgcn_mfma_f32_16x16x32_bf16(a1, b1, acc11, 0, 0, 0);
    }
    float q0 = q[b * AA + n0 + l16], q1 = q[b * AA + n0 + 16 + l16];
    float v0 = v[n0 + l16],          v1 = v[n0 + 16 + l16];
#pragma unroll
    for (int r = 0; r < 4; ++r) {
      sAcc0[r] += tanh_fast(q0 + acc00[r]) * v0 + tanh_fast(q1 + acc01[r]) * v1;
      sAcc1[r] += tanh_fast(q0 + acc10[r]) * v0 + tanh_fast(q1 + acc11[r]) * v1;
    }
  }

  // reduce over the 16 n-columns held by the quad's 16 lanes
#pragma unroll
  for (int r = 0; r < 4; ++r) {
    float v0 = sAcc0[r], v1 = sAcc1[r];
    v0 += __shfl_xor(v0, 1, 64); v1 += __shfl_xor(v1, 1, 64);
    v0 += __shfl_xor(v0, 2, 64); v1 += __shfl_xor(v1, 2, 64);
    v0 += __shfl_xor(v0, 4, 64); v1 += __shfl_xor(v1, 4, 64);
    v0 += __shfl_xor(v0, 8, 64); v1 += __shfl_xor(v1, 8, 64);
    if (l16 == 0) {
      spart[w][quad * 4 + r] = v0;
      spart[w][16 + quad * 4 + r] = v1;
    }
  }
  __syncthreads();
  if (tid < 32) {
    scores[(size_t)b * SS + s0 + tid] =
        spart[0][tid] + spart[1][tid] + spart[2][tid] + spart[3][tid];
  }
}

// one block per b: mask, softmax, in-place over the attn region
__global__ void softmax_kernel(const int* __restrict__ mask,
                               float* __restrict__ attn) {
  __shared__ float red[8];
  int b = blockIdx.x, t = threadIdx.x;
  float vals[16];
  float m = -1e30f;
  float* row = attn + (size_t)b * SS;
  const int* mrow = mask + (size_t)b * SS;
#pragma unroll
  for (int i = 0; i < 16; ++i) {
    int s = i * 256 + t;
    float x = mrow[s] ? -1e9f : row[s];
    vals[i] = x;
    m = fmaxf(m, x);
  }
  for (int off = 1; off < 64; off <<= 1) m = fmaxf(m, __shfl_xor(m, off, 64));
  int wv = t >> 6, ln = t & 63;
  if (ln == 0) red[wv] = m;
  __syncthreads();
  m = fmaxf(fmaxf(red[0], red[1]), fmaxf(red[2], red[3]));
  float sum = 0.f;
#pragma unroll
  for (int i = 0; i < 16; ++i) { vals[i] = __expf(vals[i] - m); sum += vals[i]; }
  for (int off = 1; off < 64; off <<= 1) sum += __shfl_xor(sum, off, 64);
  if (ln == 0) red[4 + wv] = sum;
  __syncthreads();
  sum = red[4] + red[5] + red[6] + red[7];
  float inv = 1.f / sum;
#pragma unroll
  for (int i = 0; i < 16; ++i) row[i * 256 + t] = vals[i] * inv;
}

// partial[b][sc][e] = sum over 128-row s-chunk of attn*enc. Grid (32 sc, 32 b).
__global__ __launch_bounds__(256) void ctx_partial_kernel(
    const float* __restrict__ enc, const float* __restrict__ attn,
    float* __restrict__ partial) {
  __shared__ float buf[512];
  int b = blockIdx.y, sc = blockIdx.x, t = threadIdx.x;
  int e4 = (t & 127) << 2;
  int sg = t >> 7;
  const float* encb = enc + ((size_t)b * SS + sc * 128) * EE;
  const float* arow = attn + (size_t)b * SS + sc * 128;
  float ax = 0.f, ay = 0.f, az = 0.f, aw = 0.f;
  for (int i = 0; i < 64; ++i) {
    int s = i * 2 + sg;
    float wgt = arow[s];
    float4 ev = *(const float4*)&encb[(size_t)s * EE + e4];
    ax += wgt * ev.x; ay += wgt * ev.y; az += wgt * ev.z; aw += wgt * ev.w;
  }
  if (sg) { buf[e4] = ax; buf[e4 + 1] = ay; buf[e4 + 2] = az; buf[e4 + 3] = aw; }
  __syncthreads();
  if (!sg) {
    float4 o;
    o.x = ax + buf[e4]; o.y = ay + buf[e4 + 1];
    o.z = az + buf[e4 + 2]; o.w = aw + buf[e4 + 3];
    *(float4*)&partial[((size_t)b * 32 + sc) * EE + e4] = o;
  }
}

// ctx[b][e] = sum_sc partial[b][sc][e]; grid 32 blocks
__global__ void ctx_reduce_kernel(const float* __restrict__ partial,
                                  float* __restrict__ ctx) {
  int b = blockIdx.x, t = threadIdx.x;
#pragma unroll
  for (int j = 0; j < 2; ++j) {
    int e = j * 256 + t;
    const float* p = partial + (size_t)b * 32 * EE + e;
    float s = 0.f;
#pragma unroll
    for (int sc = 0; sc < 32; ++sc) s += p[sc * EE];
    ctx[b * EE + e] = s;
  }
}

extern "C" void kernel_launch(void* const* d_in, const int* in_sizes, int n_in,
                              void* d_out, int out_size, void* d_ws, size_t ws_size,
                              hipStream_t stream) {
  const float* h    = (const float*)d_in[0];
  const float* enc  = (const float*)d_in[1];
  const int*   mask = (const int*)d_in[2];
  const float* Wh   = (const float*)d_in[3];
  const float* Ws   = (const float*)d_in[4];
  const float* v    = (const float*)d_in[5];

  float* out  = (float*)d_out;
  float* ctx  = out;              // [32,512]
  float* attn = out + BB * EE;    // [32,4096]

  float* qws = (float*)d_ws;                                            // 64 KB
  unsigned short* Wst =
      (unsigned short*)((char*)d_ws + (size_t)BB * AA * sizeof(float)); // 512 KB
  float* partial =
      (float*)((char*)d_ws + (size_t)BB * AA * sizeof(float)
               + (size_t)AA * EE * sizeof(unsigned short));             // 2 MB

  hipLaunchKernelGGL(query_kernel, dim3(32), dim3(256), 0, stream, h, Wh, qws);
  hipLaunchKernelGGL(wst_kernel, dim3(1024), dim3(256), 0, stream, Ws, Wst);
  hipLaunchKernelGGL(scores_kernel, dim3(SS / 32, BB), dim3(256), 0, stream,
                     enc, Wst, qws, v, attn);
  hipLaunchKernelGGL(softmax_kernel, dim3(BB), dim3(256), 0, stream, mask, attn);
  hipLaunchKernelGGL(ctx_partial_kernel, dim3(32, BB), dim3(256), 0, stream,
                     enc, attn, partial);
  hipLaunchKernelGGL(ctx_reduce_kernel, dim3(BB), dim3(256), 0, stream,
                     partial, ctx);
}

// Round 3
// 538.266 us; speedup vs baseline: 1.6602x; 1.4832x over previous
//
#include <hip/hip_runtime.h>
#include <hip/hip_bf16.h>
#include <math.h>

#define BB 32
#define SS 4096
#define EE 512
#define AA 512

typedef short bf16x8 __attribute__((ext_vector_type(8)));
typedef float f32x4 __attribute__((ext_vector_type(4)));
typedef unsigned short u16x4 __attribute__((ext_vector_type(4)));

__device__ __forceinline__ unsigned short f2bf(float f) {
  unsigned int u = __float_as_uint(f);
  u += 0x7fffu + ((u >> 16) & 1u);   // RNE (finite normals)
  return (unsigned short)(u >> 16);
}

__device__ __forceinline__ float bf2f(unsigned short s) {
  return __uint_as_float(((unsigned int)s) << 16);
}

__device__ __forceinline__ float tanh_fast(float x) {
  return 1.f - 2.f / (__expf(2.f * x) + 1.f);
}

// q[b][a] = sum_e h[b][e] * Wh[e][a]
__global__ void query_kernel(const float* __restrict__ h,
                             const float* __restrict__ Wh,
                             float* __restrict__ q) {
  __shared__ float hrow[EE];
  int b = blockIdx.x;
  int t = threadIdx.x;
  for (int i = t; i < EE; i += 256) hrow[i] = h[b * EE + i];
  __syncthreads();
  float a0 = 0.f, a1 = 0.f;
  for (int e = 0; e < EE; ++e) {
    float hv = hrow[e];
    a0 += hv * Wh[e * AA + t];
    a1 += hv * Wh[e * AA + t + 256];
  }
  q[b * AA + t] = a0;
  q[b * AA + t + 256] = a1;
}

// Wst[a][e] = bf16(Ws[e][a])
__global__ void wst_kernel(const float* __restrict__ Ws,
                           unsigned short* __restrict__ Wst) {
  int i = blockIdx.x * 256 + threadIdx.x;   // over 512*512
  int a = i >> 9, e = i & 511;
  Wst[a * EE + e] = f2bf(Ws[e * AA + a]);
}

// Fused: per block (chunk=blockIdx.x -> 64 s-rows, b=blockIdx.y):
//  A) stage enc 64x512 -> bf16 LDS (XOR-swizzled 16B chunks)
//  B) GEMM: 4 waves x (M=64, N=128), k-outer, 16 MFMA chains/k-step
//  C) tanh + v-dot -> raw masked scores; chunk max m_c; weights exp(s-m_c)
//  D) weighted column-sum of LDS tile -> ctx partial [512]
__global__ __launch_bounds__(256, 2) void fused_kernel(
    const float* __restrict__ enc, const unsigned short* __restrict__ Wst,
    const float* __restrict__ q, const float* __restrict__ v,
    const int* __restrict__ mask,
    float* __restrict__ rawscore,   // -> attn region of d_out
    float* __restrict__ ctxp,       // [32][64][512]
    float* __restrict__ mbuf) {     // [32][64]
  __shared__ __align__(16) unsigned short Atile[64 * 512];  // 64 KB
  __shared__ float spart[4][64];
  __shared__ float wrow[64];
  __shared__ float pbuf[4][512];                            // 8 KB
  const int b = blockIdx.y, chunk = blockIdx.x;
  const int s0 = chunk * 64;
  const int tid = threadIdx.x;

  // ---- Phase A: stage (2 passes x 16 float4/thread) ----
  const float4* src = (const float4*)(enc + ((size_t)b * SS + s0) * EE);
  for (int pass = 0; pass < 2; ++pass) {
#pragma unroll
    for (int i = 0; i < 16; ++i) {
      int idx = (pass * 16 + i) * 256 + tid;   // 0..8191
      float4 x = src[idx];
      int row = idx >> 7;              // 128 float4 per row
      int c4 = idx & 127;
      int ch = c4 >> 1;                // 16B chunk 0..63
      int within = (c4 & 1) * 4;
      int cs = ch ^ (row & 7);
      u16x4 p;
      p.x = f2bf(x.x); p.y = f2bf(x.y); p.z = f2bf(x.z); p.w = f2bf(x.w);
      *(u16x4*)&Atile[row * 512 + cs * 8 + within] = p;
    }
  }
  __syncthreads();

  // ---- Phase B: GEMM ----
  const int w = tid >> 6, lane = tid & 63;
  const int quad = lane >> 4, l16 = lane & 15;

  float srow[4][4];   // [m][r] partial row-scores (this lane's cols)
#pragma unroll
  for (int m = 0; m < 4; ++m)
#pragma unroll
    for (int r = 0; r < 4; ++r) srow[m][r] = 0.f;

  for (int h = 0; h < 2; ++h) {
    const int n0 = w * 128 + h * 64;
    f32x4 acc[4][4];   // [m][n]
#pragma unroll
    for (int m = 0; m < 4; ++m)
#pragma unroll
      for (int n = 0; n < 4; ++n) acc[m][n] = (f32x4){0.f, 0.f, 0.f, 0.f};

    const unsigned short* wb = Wst + (size_t)(n0 + l16) * EE + quad * 8;
#pragma unroll 2
    for (int k0 = 0; k0 < 512; k0 += 32) {
      int cs = ((k0 >> 3) + quad) ^ (l16 & 7);
      bf16x8 aF[4], bF[4];
#pragma unroll
      for (int m = 0; m < 4; ++m)
        aF[m] = *(const bf16x8*)&Atile[(m * 16 + l16) * 512 + cs * 8];
#pragma unroll
      for (int n = 0; n < 4; ++n)
        bF[n] = *(const bf16x8*)&wb[(size_t)n * 16 * EE + k0];
#pragma unroll
      for (int m = 0; m < 4; ++m)
#pragma unroll
        for (int n = 0; n < 4; ++n)
          acc[m][n] =
              __builtin_amdgcn_mfma_f32_16x16x32_bf16(aF[m], bF[n], acc[m][n], 0, 0, 0);
    }
    // epilogue: tanh + v-weighted accumulate into srow
#pragma unroll
    for (int n = 0; n < 4; ++n) {
      float qn = q[b * AA + n0 + n * 16 + l16];
      float vn = v[n0 + n * 16 + l16];
#pragma unroll
      for (int m = 0; m < 4; ++m)
#pragma unroll
        for (int r = 0; r < 4; ++r)
          srow[m][r] += tanh_fast(qn + acc[m][n][r]) * vn;
    }
  }

  // reduce over the 16 cols held by the quad's lanes
#pragma unroll
  for (int m = 0; m < 4; ++m)
#pragma unroll
    for (int r = 0; r < 4; ++r) {
      float s = srow[m][r];
      s += __shfl_xor(s, 1, 64);
      s += __shfl_xor(s, 2, 64);
      s += __shfl_xor(s, 4, 64);
      s += __shfl_xor(s, 8, 64);
      if (l16 == 0) spart[w][m * 16 + quad * 4 + r] = s;
    }
  __syncthreads();

  // ---- Phase C: masked scores, chunk max, exp weights ----
  if (tid < 64) {
    float raw = spart[0][tid] + spart[1][tid] + spart[2][tid] + spart[3][tid];
    float sc = mask[(size_t)b * SS + s0 + tid] ? -1e9f : raw;
    rawscore[(size_t)b * SS + s0 + tid] = sc;
    float mx = sc;
    for (int off = 1; off < 64; off <<= 1)
      mx = fmaxf(mx, __shfl_xor(mx, off, 64));
    wrow[tid] = __expf(sc - mx);
    if (tid == 0) mbuf[b * 64 + chunk] = mx;
  }
  __syncthreads();

  // ---- Phase D: ctx partial = sum_row wrow[row] * enc_tile[row][:] ----
  {
    const int c = tid & 63;     // e-chunk of 8
    const int sg = tid >> 6;    // 4 row-groups of 16
    float a8[8] = {0.f, 0.f, 0.f, 0.f, 0.f, 0.f, 0.f, 0.f};
#pragma unroll
    for (int i = 0; i < 16; ++i) {
      int row = sg * 16 + i;
      float wgt = wrow[row];
      bf16x8 av = *(const bf16x8*)&Atile[row * 512 + ((c ^ (row & 7)) * 8)];
#pragma unroll
      for (int j = 0; j < 8; ++j)
        a8[j] += wgt * bf2f((unsigned short)av[j]);
    }
#pragma unroll
    for (int j = 0; j < 8; ++j) pbuf[sg][c * 8 + j] = a8[j];
  }
  __syncthreads();
#pragma unroll
  for (int jj = 0; jj < 2; ++jj) {
    int e = jj * 256 + tid;
    ctxp[((size_t)b * 64 + chunk) * EE + e] =
        pbuf[0][e] + pbuf[1][e] + pbuf[2][e] + pbuf[3][e];
  }
}

// Per b: global softmax over raw scores -> attn; combine ctx partials.
__global__ void finalize_kernel(float* __restrict__ attn,
                                const float* __restrict__ ctxp,
                                const float* __restrict__ mbuf,
                                float* __restrict__ ctx) {
  __shared__ float red[8];
  __shared__ float fc[64];
  int b = blockIdx.x, t = threadIdx.x;
  float* row = attn + (size_t)b * SS;
  float vals[16];
  float m = -3e38f;
#pragma unroll
  for (int i = 0; i < 16; ++i) {
    float x = row[i * 256 + t];
    vals[i] = x;
    m = fmaxf(m, x);
  }
  for (int off = 1; off < 64; off <<= 1) m = fmaxf(m, __shfl_xor(m, off, 64));
  int wv = t >> 6, ln = t & 63;
  if (ln == 0) red[wv] = m;
  __syncthreads();
  m = fmaxf(fmaxf(red[0], red[1]), fmaxf(red[2], red[3]));
  float sum = 0.f;
#pragma unroll
  for (int i = 0; i < 16; ++i) { vals[i] = __expf(vals[i] - m); sum += vals[i]; }
  for (int off = 1; off < 64; off <<= 1) sum += __shfl_xor(sum, off, 64);
  if (ln == 0) red[4 + wv] = sum;
  __syncthreads();
  sum = red[4] + red[5] + red[6] + red[7];
  float inv = 1.f / sum;
#pragma unroll
  for (int i = 0; i < 16; ++i) row[i * 256 + t] = vals[i] * inv;

  if (t < 64) fc[t] = __expf(mbuf[b * 64 + t] - m) * inv;
  __syncthreads();
#pragma unroll
  for (int jj = 0; jj < 2; ++jj) {
    int e = jj * 256 + t;
    const float* p = ctxp + (size_t)b * 64 * EE + e;
    float s = 0.f;
#pragma unroll
    for (int c = 0; c < 64; ++c) s += fc[c] * p[c * EE];
    ctx[b * EE + e] = s;
  }
}

extern "C" void kernel_launch(void* const* d_in, const int* in_sizes, int n_in,
                              void* d_out, int out_size, void* d_ws, size_t ws_size,
                              hipStream_t stream) {
  const float* h    = (const float*)d_in[0];
  const float* enc  = (const float*)d_in[1];
  const int*   mask = (const int*)d_in[2];
  const float* Wh   = (const float*)d_in[3];
  const float* Ws   = (const float*)d_in[4];
  const float* v    = (const float*)d_in[5];

  float* out  = (float*)d_out;
  float* ctx  = out;              // [32,512]
  float* attn = out + BB * EE;    // [32,4096]

  char* ws = (char*)d_ws;
  float* qws = (float*)ws;                         ws += (size_t)BB * AA * 4;        // 64 KB
  unsigned short* Wst = (unsigned short*)ws;       ws += (size_t)AA * EE * 2;        // 512 KB
  float* ctxp = (float*)ws;                        ws += (size_t)BB * 64 * EE * 4;   // 4 MB
  float* mbuf = (float*)ws;                                                          // 8 KB

  hipLaunchKernelGGL(query_kernel, dim3(32), dim3(256), 0, stream, h, Wh, qws);
  hipLaunchKernelGGL(wst_kernel, dim3(1024), dim3(256), 0, stream, Ws, Wst);
  hipLaunchKernelGGL(fused_kernel, dim3(SS / 64, BB), dim3(256), 0, stream,
                     enc, Wst, qws, v, mask, attn, ctxp, mbuf);
  hipLaunchKernelGGL(finalize_kernel, dim3(BB), dim3(256), 0, stream,
                     attn, ctxp, mbuf, ctx);
}